// Round 4
// baseline (472.373 us; speedup 1.0000x reference)
//
#include <hip/hip_runtime.h>

#define B_   32
#define C_   16
#define H_   128
#define W_   128
#define HW_  (H_ * W_)
#define NF_  4
#define HID_ 128
#define FIN_ (C_ * NF_)   // 64
#define NPIX (B_ * HW_)   // 524288
#define TPB  512

// Kernel A: perceive (depthwise 3x3 circular conv, 4 filters) + MLP 64->128->16
// + masked update. All weights staged in LDS (41.7 KB) so per-o weight reads
// are ds_read broadcasts instead of L2-latency global/scalar loads.
__global__ __launch_bounds__(TPB, 4) void ca_step(
    const float* __restrict__ x,
    const float* __restrict__ rmask,
    const float* __restrict__ filt,
    const float* __restrict__ W1,
    const float* __restrict__ b1,
    const float* __restrict__ W2,
    const float* __restrict__ b2,
    float* __restrict__ out,
    float* __restrict__ alpha_new,
    float* __restrict__ pre_life)
{
    __shared__ float sW1[HID_ * FIN_];   // 32 KB, row-major [o][k]
    __shared__ float sW2t[HID_ * C_];    // 8 KB, transposed [o][j]
    __shared__ float sB1[HID_];
    __shared__ float sB2[C_];
    __shared__ float sF[NF_ * 9];

    for (int i = threadIdx.x; i < HID_ * FIN_; i += TPB) sW1[i] = W1[i];
    for (int i = threadIdx.x; i < C_ * HID_; i += TPB) {
        int j = i >> 7;            // row of W2
        int o = i & (HID_ - 1);    // col of W2
        sW2t[o * C_ + j] = W2[i];
    }
    if (threadIdx.x < HID_) sB1[threadIdx.x] = b1[threadIdx.x];
    if (threadIdx.x < C_)   sB2[threadIdx.x] = b2[threadIdx.x];
    if (threadIdx.x < NF_ * 9) sF[threadIdx.x] = filt[threadIdx.x];
    __syncthreads();

    int tid = blockIdx.x * TPB + threadIdx.x;
    if (tid >= NPIX) return;
    int b   = tid >> 14;          // / HW_
    int pix = tid & (HW_ - 1);
    int r   = pix >> 7;           // / W_
    int c   = pix & (W_ - 1);

    int rm = (r - 1) & (H_ - 1), rp = (r + 1) & (H_ - 1);
    int cm = (c - 1) & (W_ - 1), cp = (c + 1) & (W_ - 1);
    int off[9] = { rm * W_ + cm, rm * W_ + c, rm * W_ + cp,
                   r  * W_ + cm, r  * W_ + c, r  * W_ + cp,
                   rp * W_ + cm, rp * W_ + c, rp * W_ + cp };

    const float* xb = x + (size_t)b * C_ * HW_;

    float y[FIN_];
    float premax = -1e30f, presum = 0.f;

    #pragma unroll
    for (int ch = 0; ch < C_; ++ch) {
        const float* xc = xb + ch * HW_;
        float n[9];
        #pragma unroll
        for (int t = 0; t < 9; ++t) n[t] = xc[off[t]];
        #pragma unroll
        for (int f = 0; f < NF_; ++f) {
            float a = 0.f;
            #pragma unroll
            for (int t = 0; t < 9; ++t) a = fmaf(sF[f * 9 + t], n[t], a);
            y[ch * NF_ + f] = a;
        }
        if (ch == 3) {
            float mx = n[0], sm = 0.f;
            #pragma unroll
            for (int t = 0; t < 9; ++t) { mx = fmaxf(mx, n[t]); sm += n[t]; }
            premax = mx; presum = sm;
        }
    }
    float pre = (premax > 0.1f && (presum * (1.0f / 9.0f)) < 0.2f) ? 1.f : 0.f;

    // MLP: h = leaky(W1 @ y + b1); dx = W2 @ h + b2
    // 4 partials: dependent chain 16 deep (64 cyc) < 160 cyc issue work/iter.
    float acc[C_];
    #pragma unroll
    for (int j = 0; j < C_; ++j) acc[j] = sB2[j];

    #pragma unroll 1
    for (int o = 0; o < HID_; ++o) {
        const float* w1r = &sW1[o * FIN_];
        float p0 = 0.f, p1 = 0.f, p2 = 0.f, p3 = 0.f;
        #pragma unroll
        for (int k = 0; k < FIN_; k += 4) {
            p0 = fmaf(w1r[k + 0], y[k + 0], p0);
            p1 = fmaf(w1r[k + 1], y[k + 1], p1);
            p2 = fmaf(w1r[k + 2], y[k + 2], p2);
            p3 = fmaf(w1r[k + 3], y[k + 3], p3);
        }
        float t = sB1[o] + ((p0 + p1) + (p2 + p3));
        float h = (t >= 0.f) ? t : 0.01f * t;
        const float* w2r = &sW2t[o * C_];
        #pragma unroll
        for (int j = 0; j < C_; ++j) acc[j] = fmaf(w2r[j], h, acc[j]);
    }

    float um = (rmask[b * HW_ + pix] <= 0.5f) ? 1.f : 0.f;

    float* ob = out + (size_t)b * C_ * HW_ + pix;
    float an = 0.f;
    #pragma unroll
    for (int ch = 0; ch < C_; ++ch) {
        float xv = xb[ch * HW_ + off[4]];
        float xn = xv + acc[ch] * um;
        ob[ch * HW_] = xn;
        if (ch == 3) an = xn;
    }
    alpha_new[tid] = an;
    pre_life[tid]  = pre;
}

// Kernel B: post_life from new alpha plane; zero channels where !(pre & post).
__global__ __launch_bounds__(256) void ca_mask(
    const float* __restrict__ alpha_new,
    const float* __restrict__ pre_life,
    float* __restrict__ out)
{
    int tid = blockIdx.x * blockDim.x + threadIdx.x;
    if (tid >= NPIX) return;
    int b   = tid >> 14;
    int pix = tid & (HW_ - 1);
    int r   = pix >> 7;
    int c   = pix & (W_ - 1);

    int rm = (r - 1) & (H_ - 1), rp = (r + 1) & (H_ - 1);
    int cm = (c - 1) & (W_ - 1), cp = (c + 1) & (W_ - 1);
    int off[9] = { rm * W_ + cm, rm * W_ + c, rm * W_ + cp,
                   r  * W_ + cm, r  * W_ + c, r  * W_ + cp,
                   rp * W_ + cm, rp * W_ + c, rp * W_ + cp };

    const float* ab = alpha_new + (size_t)b * HW_;
    float mx = -1e30f, sm = 0.f;
    #pragma unroll
    for (int t = 0; t < 9; ++t) {
        float v = ab[off[t]];
        mx = fmaxf(mx, v);
        sm += v;
    }
    bool post = (mx > 0.1f) && ((sm * (1.0f / 9.0f)) < 0.2f);
    bool life = post && (pre_life[tid] > 0.5f);
    if (!life) {
        float* ob = out + (size_t)b * C_ * HW_ + pix;
        #pragma unroll
        for (int ch = 0; ch < C_; ++ch) ob[ch * HW_] = 0.f;
    }
}

extern "C" void kernel_launch(void* const* d_in, const int* in_sizes, int n_in,
                              void* d_out, int out_size, void* d_ws, size_t ws_size,
                              hipStream_t stream)
{
    const float* x     = (const float*)d_in[0];
    const float* rmask = (const float*)d_in[1];
    const float* filt  = (const float*)d_in[2];
    const float* W1    = (const float*)d_in[3];
    const float* b1    = (const float*)d_in[4];
    const float* W2    = (const float*)d_in[5];
    const float* b2    = (const float*)d_in[6];
    float* out = (float*)d_out;

    float* alpha_new = (float*)d_ws;           // NPIX floats
    float* pre_life  = alpha_new + NPIX;       // NPIX floats

    ca_step<<<dim3(NPIX / TPB), dim3(TPB), 0, stream>>>(
        x, rmask, filt, W1, b1, W2, b2, out, alpha_new, pre_life);
    ca_mask<<<dim3(NPIX / 256), dim3(256), 0, stream>>>(alpha_new, pre_life, out);
}

// Round 5
// 248.219 us; speedup vs baseline: 1.9030x; 1.9030x over previous
//
#include <hip/hip_runtime.h>

#define B_   32
#define C_   16
#define H_   128
#define W_   128
#define HW_  (H_ * W_)
#define NF_  4
#define HID_ 128
#define FIN_ (C_ * NF_)   // 64
#define NPIX (B_ * HW_)   // 524288
#define TPB  256

// Kernel A: perceive (depthwise 3x3 circular conv, 4 filters) + MLP 64->128->16
// + masked update. W1 + W2^T staged in LDS (exactly 40 KB -> up to 4 blocks/CU);
// b1/b2/filters stay as K$-resident scalar loads (<1 KB total, never evicted).
// __launch_bounds__(256,4): VGPR cap 128 -> 4 waves/SIMD, no forced spills
// (R4's (512,4) capped VGPR at 64 and spilled y[64] to scratch: 870 MB traffic).
__global__ __launch_bounds__(TPB, 4) void ca_step(
    const float* __restrict__ x,
    const float* __restrict__ rmask,
    const float* __restrict__ filt,
    const float* __restrict__ W1,
    const float* __restrict__ b1,
    const float* __restrict__ W2,
    const float* __restrict__ b2,
    float* __restrict__ out,
    float* __restrict__ alpha_new,
    float* __restrict__ pre_life)
{
    __shared__ float sW1[HID_ * FIN_];   // 32 KB, row-major [o][k]
    __shared__ float sW2t[HID_ * C_];    // 8 KB, transposed [o][j]

    // Stage W1 with float4 loads (2048 float4 / 256 threads = 8 each).
    {
        const float4* src = (const float4*)W1;
        float4* dst = (float4*)sW1;
        #pragma unroll
        for (int i = 0; i < 8; ++i)
            dst[threadIdx.x + i * TPB] = src[threadIdx.x + i * TPB];
        // W2 [16][128] -> sW2t [128][16]; write stride 16 floats = 2-way bank
        // alias (free per m136).
        #pragma unroll
        for (int i = 0; i < 8; ++i) {
            int t = threadIdx.x + i * TPB;   // 0..2047
            int j = t >> 7;                  // row of W2
            int o = t & (HID_ - 1);          // col of W2
            sW2t[o * C_ + j] = W2[t];
        }
    }
    __syncthreads();

    int tid = blockIdx.x * TPB + threadIdx.x;
    int b   = tid >> 14;          // / HW_
    int pix = tid & (HW_ - 1);
    int r   = pix >> 7;           // / W_
    int c   = pix & (W_ - 1);

    int rm = (r - 1) & (H_ - 1), rp = (r + 1) & (H_ - 1);
    int cm = (c - 1) & (W_ - 1), cp = (c + 1) & (W_ - 1);
    int off[9] = { rm * W_ + cm, rm * W_ + c, rm * W_ + cp,
                   r  * W_ + cm, r  * W_ + c, r  * W_ + cp,
                   rp * W_ + cm, rp * W_ + c, rp * W_ + cp };

    const float* xb = x + (size_t)b * C_ * HW_;

    float y[FIN_];
    float premax = -1e30f, presum = 0.f;

    #pragma unroll
    for (int ch = 0; ch < C_; ++ch) {
        const float* xc = xb + ch * HW_;
        float n[9];
        #pragma unroll
        for (int t = 0; t < 9; ++t) n[t] = xc[off[t]];
        #pragma unroll
        for (int f = 0; f < NF_; ++f) {
            float a = 0.f;
            #pragma unroll
            for (int t = 0; t < 9; ++t) a = fmaf(filt[f * 9 + t], n[t], a);
            y[ch * NF_ + f] = a;
        }
        if (ch == 3) {
            float mx = n[0], sm = 0.f;
            #pragma unroll
            for (int t = 0; t < 9; ++t) { mx = fmaxf(mx, n[t]); sm += n[t]; }
            premax = mx; presum = sm;
        }
    }
    float pre = (premax > 0.1f && (presum * (1.0f / 9.0f)) < 0.2f) ? 1.f : 0.f;

    // MLP: h = leaky(W1 @ y + b1); dx = W2 @ h + b2
    // Per o: 16 broadcast ds_read_b128 (LDS pipe, overlaps other waves' VALU)
    // + 64 L1-FMAs in 4 independent 16-deep chains + 16 acc-FMAs.
    float acc[C_];
    #pragma unroll
    for (int j = 0; j < C_; ++j) acc[j] = b2[j];

    #pragma unroll 1
    for (int o = 0; o < HID_; ++o) {
        const float4* w4 = (const float4*)&sW1[o * FIN_];
        float p0 = 0.f, p1 = 0.f, p2 = 0.f, p3 = 0.f;
        #pragma unroll
        for (int i = 0; i < FIN_ / 4; ++i) {
            float4 w = w4[i];
            p0 = fmaf(w.x, y[4 * i + 0], p0);
            p1 = fmaf(w.y, y[4 * i + 1], p1);
            p2 = fmaf(w.z, y[4 * i + 2], p2);
            p3 = fmaf(w.w, y[4 * i + 3], p3);
        }
        float t = b1[o] + ((p0 + p1) + (p2 + p3));
        float h = (t >= 0.f) ? t : 0.01f * t;
        const float4* w2r = (const float4*)&sW2t[o * C_];
        #pragma unroll
        for (int jq = 0; jq < C_ / 4; ++jq) {
            float4 w = w2r[jq];
            acc[4 * jq + 0] = fmaf(w.x, h, acc[4 * jq + 0]);
            acc[4 * jq + 1] = fmaf(w.y, h, acc[4 * jq + 1]);
            acc[4 * jq + 2] = fmaf(w.z, h, acc[4 * jq + 2]);
            acc[4 * jq + 3] = fmaf(w.w, h, acc[4 * jq + 3]);
        }
    }

    float um = (rmask[b * HW_ + pix] <= 0.5f) ? 1.f : 0.f;

    float* ob = out + (size_t)b * C_ * HW_ + pix;
    float an = 0.f;
    #pragma unroll
    for (int ch = 0; ch < C_; ++ch) {
        float xv = xb[ch * HW_ + off[4]];
        float xn = xv + acc[ch] * um;
        ob[ch * HW_] = xn;
        if (ch == 3) an = xn;
    }
    alpha_new[tid] = an;
    pre_life[tid]  = pre;
}

// Kernel B: post_life from new alpha plane; zero channels where !(pre & post).
__global__ __launch_bounds__(256) void ca_mask(
    const float* __restrict__ alpha_new,
    const float* __restrict__ pre_life,
    float* __restrict__ out)
{
    int tid = blockIdx.x * blockDim.x + threadIdx.x;
    if (tid >= NPIX) return;
    int b   = tid >> 14;
    int pix = tid & (HW_ - 1);
    int r   = pix >> 7;
    int c   = pix & (W_ - 1);

    int rm = (r - 1) & (H_ - 1), rp = (r + 1) & (H_ - 1);
    int cm = (c - 1) & (W_ - 1), cp = (c + 1) & (W_ - 1);
    int off[9] = { rm * W_ + cm, rm * W_ + c, rm * W_ + cp,
                   r  * W_ + cm, r  * W_ + c, r  * W_ + cp,
                   rp * W_ + cm, rp * W_ + c, rp * W_ + cp };

    const float* ab = alpha_new + (size_t)b * HW_;
    float mx = -1e30f, sm = 0.f;
    #pragma unroll
    for (int t = 0; t < 9; ++t) {
        float v = ab[off[t]];
        mx = fmaxf(mx, v);
        sm += v;
    }
    bool post = (mx > 0.1f) && ((sm * (1.0f / 9.0f)) < 0.2f);
    bool life = post && (pre_life[tid] > 0.5f);
    if (!life) {
        float* ob = out + (size_t)b * C_ * HW_ + pix;
        #pragma unroll
        for (int ch = 0; ch < C_; ++ch) ob[ch * HW_] = 0.f;
    }
}

extern "C" void kernel_launch(void* const* d_in, const int* in_sizes, int n_in,
                              void* d_out, int out_size, void* d_ws, size_t ws_size,
                              hipStream_t stream)
{
    const float* x     = (const float*)d_in[0];
    const float* rmask = (const float*)d_in[1];
    const float* filt  = (const float*)d_in[2];
    const float* W1    = (const float*)d_in[3];
    const float* b1    = (const float*)d_in[4];
    const float* W2    = (const float*)d_in[5];
    const float* b2    = (const float*)d_in[6];
    float* out = (float*)d_out;

    float* alpha_new = (float*)d_ws;           // NPIX floats
    float* pre_life  = alpha_new + NPIX;       // NPIX floats

    ca_step<<<dim3(NPIX / TPB), dim3(TPB), 0, stream>>>(
        x, rmask, filt, W1, b1, W2, b2, out, alpha_new, pre_life);
    ca_mask<<<dim3(NPIX / 256), dim3(256), 0, stream>>>(alpha_new, pre_life, out);
}